// Round 19
// baseline (121.912 us; speedup 1.0000x reference)
//
#include <hip/hip_runtime.h>
#include <hip/hip_bf16.h>

#define NCOLS 32768
#define NZ 64
#define NT 40
#define DTF 30.0f
#define GAMMAC 0.55f

typedef _Float16 f16;

// Cap the pre-RA scheduler's prefetch window (r4->r5 lesson).
#define SBAR() __builtin_amdgcn_sched_barrier(0)

// lane^1 within quad: u<->v (t<->s) partner
__device__ __forceinline__ float dpp1(float x) {
    return __int_as_float(__builtin_amdgcn_mov_dpp(__float_as_int(x), 0xB1, 0xF, 0xF, true));
}
// lane^2 within quad: top<->bottom half exchange
__device__ __forceinline__ float dpp2(float x) {
    return __int_as_float(__builtin_amdgcn_mov_dpp(__float_as_int(x), 0x4E, 0xF, 0xF, true));
}
__device__ __forceinline__ unsigned int packh2(float a, float b) {
    union { f16 h[2]; unsigned int u; } v;
    v.h[0] = (f16)a; v.h[1] = (f16)b; return v.u;
}
__device__ __forceinline__ unsigned short f16bits(float a) {
    union { f16 h; unsigned short u; } v; v.h = (f16)a; return v.u;
}
__device__ __forceinline__ float lo16f(unsigned int x) {
    union { unsigned int u; f16 h[2]; } v; v.u = x; return (float)v.h[0];
}
__device__ __forceinline__ float hi16f(unsigned int x) {
    union { unsigned int u; f16 h[2]; } v; v.u = x; return (float)v.h[1];
}

// r19 = r9's BABE (math PROVEN: absmax 0.25) + widened CP/FG (b128 = 8
// levels/read -> 16 ds ops/thread-step) + amdgpu_num_vgpr(96).
// r14-r18 lesson: the 2-waves/SIMD envelope is latency-bound (~2x over the
// balanced 38us VALU/LDS floors); the fix is BABE's 16 waves/CU + 32-level
// chains, which was blocked ONLY by the allocator clamping small-LDS
// kernels to 56 VGPRs (r9/r10: 300MB spill). amdgpu_num_vgpr sets the RA
// budget explicitly -- the one knob not yet pulled. Demand ~72 < 96.
// LDS 40KB -> 4 blocks/CU = 16 waves/CU.
__global__ __launch_bounds__(256, 2)
__attribute__((amdgpu_num_vgpr(96)))
void scm_kernel(
    const float* __restrict__ u0, const float* __restrict__ v0,
    const float* __restrict__ t0, const float* __restrict__ s0,
    const float* __restrict__ hz, const float* __restrict__ akv,
    const float* __restrict__ akt, const float* __restrict__ tfo,
    const float* __restrict__ sfo, const float* __restrict__ uss,
    const float* __restrict__ vss, const float* __restrict__ usb,
    const float* __restrict__ vsb, const float* __restrict__ fcor,
    float* __restrict__ out)
{
    __shared__ uint4 Wsh[8 * 128];    // [j4][slot] 4 lvls (hg,-e)   = 16KB
    __shared__ uint4 CP4sh[4 * 128];  // [j8][slot] 8 lvls -cp|-eq   =  8KB
    __shared__ uint4 FG4sh[4 * 256];  // [j8][ltid] 8 lvls fg        = 16KB

    const int ltid = threadIdx.x;
    const int cb   = ltid >> 3;            // column in block 0..31
    const int sub  = ltid & 7;
    const int f01  = sub & 1;              // 0: u/t   1: v/s
    const int half = (sub >> 1) & 1;       // 0: top(k=0..31) 1: bottom(63..32)
    const int pr   = sub >> 2;             // 0: uv (akv)  1: ts (akt)
    const int field = pr * 2 + f01;
    const int col  = blockIdx.x * 32 + cb;
    const int slot = (cb << 2) | (pr << 1) | half;   // 0..127

    const float* ak  = pr ? akt : akv;
    const float* st0 = (field == 0) ? u0 : (field == 1) ? v0
                     : (field == 2) ? t0 : s0;

    // Coriolis scalars + boundary forcing (uv lanes; ts: alpha=1,beta=0)
    float alpha = 1.0f, beta = 0.0f, bndv = 0.0f;
    {
        float fc   = fcor[col];
        float dtfc = DTF * fc;
        float cff  = dtfc * dtfc;
        float cff1 = 1.0f / (1.0f + GAMMAC * GAMMAC * cff);
        float coefc = 1.0f - GAMMAC * (1.0f - GAMMAC) * cff;
        if (!pr) {
            alpha = cff1 * coefc;
            beta  = f01 ? -cff1 * dtfc : cff1 * dtfc;
            bndv  = half ?  DTF * ((f01 ? vss : uss)[col])
                         : -DTF * ((f01 ? vsb : usb)[col]);
        }
    }

    const float* hzc = hz + (size_t)col * NZ;
    const float* akc = ak + (size_t)col * (NZ + 1);
    const float* frc = (f01 ? sfo : tfo) + (size_t)col * NZ;

    // ---- build: affine indexing, separate top/bottom loops, 8-lvl packed ----
    float cpn_own = 0.0f;   // junction: top -cp[31], bottom -eq[32] (f32)
    if (!half) {
        float chainprev = 0.f, carry = 0.f, hk = hzc[0];
        uint4 wacc = {}; uint4 c8 = {}, f8 = {};
        #pragma unroll
        for (int j = 0; j < 32; ++j) {
            float hnx = hzc[j + 1];
            float adj = (-2.0f * DTF) * akc[j + 1] / (hk + hnx);
            float b   = hk - carry - adj;
            float g   = 1.0f / (b - carry * chainprev);
            float fgk = pr ? (DTF * frc[j]) * g
                           : ((j == 0) ? bndv * g : 0.0f);
            unsigned int   wv  = packh2(hk * g, -carry * g);
            float          cpn = -(adj * g);
            unsigned short cv  = f16bits(cpn);
            unsigned short fv  = f16bits(fgk);
            switch (j & 7) {
                case 0: wacc.x = wv; c8.x = cv; f8.x = fv; break;
                case 1: wacc.y = wv; c8.x |= ((unsigned)cv << 16);
                        f8.x |= ((unsigned)fv << 16); break;
                case 2: wacc.z = wv; c8.y = cv; f8.y = fv; break;
                case 3: wacc.w = wv; c8.y |= ((unsigned)cv << 16);
                        f8.y |= ((unsigned)fv << 16);
                        if (f01 == 0) Wsh[(j >> 2) * 128 + slot] = wacc;
                        break;
                case 4: wacc.x = wv; c8.z = cv; f8.z = fv; break;
                case 5: wacc.y = wv; c8.z |= ((unsigned)cv << 16);
                        f8.z |= ((unsigned)fv << 16); break;
                case 6: wacc.z = wv; c8.w = cv; f8.w = fv; break;
                default:
                    wacc.w = wv; c8.w |= ((unsigned)cv << 16);
                    f8.w |= ((unsigned)fv << 16);
                    FG4sh[(j >> 3) * 256 + ltid] = f8;
                    if (f01 == 0) {
                        Wsh[(j >> 2) * 128 + slot]   = wacc;
                        CP4sh[(j >> 3) * 128 + slot] = c8;
                    }
                    break;
            }
            if (j == 31) cpn_own = cpn;
            chainprev = adj * g; carry = adj; hk = hnx;
            if ((j & 15) == 15) SBAR();
        }
    } else {
        float chainprev = 0.f, carry = 0.f, hk = hzc[63];
        uint4 wacc = {}; uint4 c8 = {}, f8 = {};
        #pragma unroll
        for (int j = 0; j < 32; ++j) {
            float hnx = hzc[62 - j];
            float adj = (-2.0f * DTF) * akc[63 - j] / (hk + hnx);
            float b   = hk - carry - adj;
            float g   = 1.0f / (b - carry * chainprev);
            float fgk = pr ? (DTF * frc[63 - j]) * g
                           : ((j == 0) ? bndv * g : 0.0f);
            unsigned int   wv  = packh2(hk * g, -carry * g);
            float          cpn = -(adj * g);
            unsigned short cv  = f16bits(cpn);
            unsigned short fv  = f16bits(fgk);
            switch (j & 7) {
                case 0: wacc.x = wv; c8.x = cv; f8.x = fv; break;
                case 1: wacc.y = wv; c8.x |= ((unsigned)cv << 16);
                        f8.x |= ((unsigned)fv << 16); break;
                case 2: wacc.z = wv; c8.y = cv; f8.y = fv; break;
                case 3: wacc.w = wv; c8.y |= ((unsigned)cv << 16);
                        f8.y |= ((unsigned)fv << 16);
                        if (f01 == 0) Wsh[(j >> 2) * 128 + slot] = wacc;
                        break;
                case 4: wacc.x = wv; c8.z = cv; f8.z = fv; break;
                case 5: wacc.y = wv; c8.z |= ((unsigned)cv << 16);
                        f8.z |= ((unsigned)fv << 16); break;
                case 6: wacc.z = wv; c8.w = cv; f8.w = fv; break;
                default:
                    wacc.w = wv; c8.w |= ((unsigned)cv << 16);
                    f8.w |= ((unsigned)fv << 16);
                    FG4sh[(j >> 3) * 256 + ltid] = f8;
                    if (f01 == 0) {
                        Wsh[(j >> 2) * 128 + slot]   = wacc;
                        CP4sh[(j >> 3) * 128 + slot] = c8;
                    }
                    break;
            }
            if (j == 31) cpn_own = cpn;
            chainprev = adj * g; carry = adj; hk = hnx;
            if ((j & 15) == 15) SBAR();
        }
    }

    // junction constants: s = 1/(1 - cp31*eq32)
    float cpn_oth = dpp2(cpn_own);
    float cptop   = half ? cpn_oth : cpn_own;
    float cpbot   = half ? cpn_own : cpn_oth;
    float smid    = 1.0f / (1.0f - cptop * cpbot);

    // ---- load state (local order; bottom reversed) ----
    float tau[32];
    {
        const float4* sp = (const float4*)(st0 + (size_t)col * NZ);
        if (!half) {
            #pragma unroll
            for (int q = 0; q < 8; ++q) {
                float4 v = sp[q];
                tau[4*q+0] = v.x; tau[4*q+1] = v.y;
                tau[4*q+2] = v.z; tau[4*q+3] = v.w;
            }
        } else {
            #pragma unroll
            for (int q = 0; q < 8; ++q) {
                float4 v = sp[15 - q];
                tau[4*q+0] = v.w; tau[4*q+1] = v.z;
                tau[4*q+2] = v.y; tau[4*q+3] = v.x;
            }
        }
    }

    // deviation shift for t,s: column mean via one dpp2 exchange
    float meanadd = 0.0f;
    {
        float ss = 0.f;
        #pragma unroll
        for (int j = 0; j < 32; ++j) ss += tau[j];
        float tot = ss + dpp2(ss);
        if (pr) {
            meanadd = tot * (1.0f / 64.0f);
            #pragma unroll
            for (int j = 0; j < 32; ++j) tau[j] -= meanadd;
        }
    }

    __syncthreads();   // coefficients published; LDS read-only from here on

    // ---- 40 time steps ----
    for (int n = 0; n < NT; ++n) {
        // elimination sweep (both halves toward the junction)
        float dpprev = 0.f;
        uint4 f8;
        #pragma unroll
        for (int q = 0; q < 8; ++q) {
            uint4 w = Wsh[q * 128 + slot];
            if ((q & 1) == 0) f8 = FG4sh[(q >> 1) * 256 + ltid];
            #pragma unroll
            for (int i = 0; i < 4; ++i) {
                unsigned wv = (i == 0) ? w.x : (i == 1) ? w.y
                            : (i == 2) ? w.z : w.w;
                const int sel = ((q & 1) << 1) | (i >> 1);
                unsigned fgw = (sel == 0) ? f8.x : (sel == 1) ? f8.y
                             : (sel == 2) ? f8.z : f8.w;
                float fgv = (i & 1) ? hi16f(fgw) : lo16f(fgw);
                float own = tau[4*q + i];
                float oth = dpp1(own);                    // u<->v partner
                float m   = fmaf(beta, oth, alpha * own); // ts: beta=0,alpha=1
                float t1  = fmaf(lo16f(wv), m, fgv);      // off-chain
                float dp  = fmaf(hi16f(wv), dpprev, t1);  // chain: ONE fma
                tau[4*q + i] = dp;
                dpprev = dp;
            }
            if ((q & 3) == 3) SBAR();
        }
        // junction 2x2: x31 = s*(dp31 - cp31*dq32); x32 = dq32 - eq32*x31
        float other = dpp2(dpprev);
        float dtp = half ? other : dpprev;    // dp31
        float dbt = half ? dpprev : other;    // dq32
        float x31 = smid * fmaf(cptop, dbt, dtp);
        float xj  = half ? fmaf(cpn_own, x31, dpprev) : x31;
        tau[31] = xj;
        // substitution outward (both halves away from the junction)
        float xn = xj;
        #pragma unroll
        for (int qq = 3; qq >= 0; --qq) {
            uint4 c8 = CP4sh[qq * 128 + slot];
            #pragma unroll
            for (int i = 7; i >= 0; --i) {
                const int j = 8*qq + i;
                if (j == 31) continue;        // junction already solved
                unsigned cw = ((i >> 1) == 0) ? c8.x : ((i >> 1) == 1) ? c8.y
                            : ((i >> 1) == 2) ? c8.z : c8.w;
                float cv = (i & 1) ? hi16f(cw) : lo16f(cw);
                float x = fmaf(cv, xn, tau[j]);
                tau[j] = x;
                xn = x;
            }
            if ((qq & 1) == 0) SBAR();
        }
    }

    // ---- store f32 output: out[field][col][k] (bottom reversed) ----
    float* op = out + ((size_t)field * NCOLS + col) * NZ;
    if (!half) {
        #pragma unroll
        for (int q = 0; q < 8; ++q) {
            float4 w;
            w.x = tau[4*q+0] + meanadd; w.y = tau[4*q+1] + meanadd;
            w.z = tau[4*q+2] + meanadd; w.w = tau[4*q+3] + meanadd;
            ((float4*)op)[q] = w;
        }
    } else {
        #pragma unroll
        for (int q = 0; q < 8; ++q) {
            float4 w;
            w.x = tau[4*q+3] + meanadd; w.y = tau[4*q+2] + meanadd;
            w.z = tau[4*q+1] + meanadd; w.w = tau[4*q+0] + meanadd;
            ((float4*)op)[15 - q] = w;
        }
    }
}

extern "C" void kernel_launch(void* const* d_in, const int* in_sizes, int n_in,
                              void* d_out, int out_size, void* d_ws, size_t ws_size,
                              hipStream_t stream) {
    const float* u0   = (const float*)d_in[0];
    const float* v0   = (const float*)d_in[1];
    const float* t0   = (const float*)d_in[2];
    const float* s0   = (const float*)d_in[3];
    const float* hz   = (const float*)d_in[4];
    const float* akv  = (const float*)d_in[5];
    const float* akt  = (const float*)d_in[6];
    const float* tfo  = (const float*)d_in[7];
    const float* sfo  = (const float*)d_in[8];
    const float* uss  = (const float*)d_in[9];
    const float* vss  = (const float*)d_in[10];
    const float* usb  = (const float*)d_in[11];
    const float* vsb  = (const float*)d_in[12];
    const float* fcor = (const float*)d_in[13];

    scm_kernel<<<dim3(NCOLS / 32), dim3(256), 0, stream>>>(
        u0, v0, t0, s0, hz, akv, akt, tfo, sfo, uss, vss, usb, vsb, fcor,
        (float*)d_out);
}